// Round 5
// baseline (469.883 us; speedup 1.0000x reference)
//
#include <hip/hip_runtime.h>

// HMS2 fused v6: conv1+conv2 on MFMA; im2col phase ELIMINATED -- conv1 MFMA
// B-frags read directly from f16 staged image via K-reordered W1T:
//   khat = {row0 w0..7 | row1 w0..7 | row2 w0..7 | w8r0,w8r1,w8r2,bias,0,0,0,0}
// LDS = s_imgf16(7424) + s_c1(18560) = 25984 B -> 6 blocks/CU (24 waves).
// Epilogue transposes in two 64-channel halves (s_ep 64x66 f32, unioned).
// Weight transforms merged into one launch, w2 reads coalesced.

#define IMG 2304
#define H1  1152
#define H2  576
#define C1  64
#define C2  128
#define TS  8
#define NTB (H2/TS)        // 72
#define C1T 17
#define IT  35
#define IRS 212            // s_imgf16 row stride bytes (35*3*2=210 -> 212)
#define C1OFF 7424         // s_c1 base byte offset (128B aligned)

typedef __bf16 bf16_t;
typedef __bf16 bf16x8 __attribute__((ext_vector_type(8)));
typedef __bf16 bf16x4 __attribute__((ext_vector_type(4)));
typedef _Float16 f16_t;
typedef _Float16 f16x8 __attribute__((ext_vector_type(8)));
typedef float  f32x16 __attribute__((ext_vector_type(16)));
typedef unsigned int uint32;
typedef uint32 u32x4 __attribute__((ext_vector_type(4)));

#define W2T_BYTES (C2*576*2)     // 147456

// paired-row swizzle for s_c1: s = logical row (64B payload), g = 16B group 0..3
#define SWZ(s, g) ( (((s)>>1)*128) + (((((g) + (((s)&1)<<2) + (((s)>>1)&7)) & 7)) << 4) )

// ---- merged weight transform: blocks 0..287 = W2 (coalesced reads),
//      block 288 = W1 (khat-reordered, bias at khat=27) ----
__global__ __launch_bounds__(256) void weights_transform(
    const float* __restrict__ W2, const float* __restrict__ W1,
    const float* __restrict__ b1,
    bf16_t* __restrict__ W2T, f16_t* __restrict__ W1T)
{
    if (blockIdx.x < 288) {
        int src = blockIdx.x*256 + threadIdx.x;            // linear over W2
        int n = src & 127, ci = (src >> 7) & 63, kykx = src >> 13;
        int p = ci >> 5, chh = (ci >> 4) & 1, kg = (ci >> 3) & 1, e = ci & 7;
        W2T[((((p*9 + kykx) << 2) + (chh << 1) + kg) << 10) + (n << 3) + e]
            = (bf16_t)W2[src];
    } else {
        int t = threadIdx.x;
        int oc = t & 63, grp = t >> 6;
        #pragma unroll
        for (int j = 0; j < 8; ++j) {
            int kh = grp*8 + j;
            float v;
            if (kh < 24)       v = W1[(9*(kh >> 3) + (kh & 7))*C1 + oc];
            else if (kh == 24) v = W1[ 8*C1 + oc];
            else if (kh == 25) v = W1[17*C1 + oc];
            else if (kh == 26) v = W1[26*C1 + oc];
            else if (kh == 27) v = b1[oc];
            else               v = 0.f;
            W1T[oc*32 + kh] = (f16_t)v;
        }
    }
}

__global__ __launch_bounds__(256, 6) void hms2_fused(
    const int*    __restrict__ img,
    const float*  __restrict__ b2,
    const bf16_t* __restrict__ W2T,
    const f16_t*  __restrict__ W1T,
    float*        __restrict__ out)
{
    __shared__ __align__(16) char s_raw[25984];
    // s_imgf16: row r (0..34) at byte r*IRS + 2*w, w = col*3+ch (0..104)
    char*  s_c1b = s_raw + C1OFF;               // [289 rows][64B] SWZ = 18560 B
    float* s_ep  = (float*)s_raw;               // 64*66 f32 = 16896 B (union)

    const int tid   = threadIdx.x;
    const int tileY = blockIdx.x / NTB;
    const int tileX = blockIdx.x % NTB;
    const int e0y = tileY*TS, e0x = tileX*TS;
    const int r0  = 2*e0y,    q0  = 2*e0x;
    const int iy0 = 4*e0y,    ix0 = 4*e0x;

    // ---- stage image tile as f16, normalized, zero-padded past image edge ----
    const int cb = ix0*3;                        // word base within image row
    for (int i = tid; i < 35*105; i += 256) {
        int r = i/105, w = i - 105*r;
        float v = 0.f;
        if ((iy0 + r < IMG) && (cb + w < IMG*3))
            v = (float)img[(size_t)(iy0 + r)*(IMG*3) + cb + w] * (1.f/255.f);
        *(f16_t*)(s_raw + r*IRS + 2*w) = (f16_t)v;
    }

    // ---- MFMA lane identities ----
    const int lane = tid & 63;
    const int m    = lane & 31;
    const int kg   = lane >> 5;
    const int cg   = __builtin_amdgcn_readfirstlane(tid >> 6);

    const int h0  = m >> 3, w0 = m & 7;
    const int s00 = 34*h0 + 2*w0;
    const bf16_t* bBase = W2T + (size_t)kg*1024 + (size_t)(cg*32 + m)*8;

    f32x16 acc0, acc1;
    #pragma unroll
    for (int r = 0; r < 16; ++r) { acc0[r] = 0.f; acc1[r] = 0.f; }

    __syncthreads();

    #pragma unroll 1
    for (int p = 0; p < 2; ++p) {
        // conv1 A-frags: W1T rows = out-channels [32p, 32p+32), khat order
        const f16_t* w1p = W1T + (size_t)(p*32 + m)*32 + kg*8;
        f16x8 wA = *(const f16x8*)(w1p);
        f16x8 wB = *(const f16x8*)(w1p + 16);

        // ---- conv1: B-frags direct from s_imgf16; D[ch][spatial] -> s_c1 ----
        for (int sf = cg; sf < 10; sf += 4) {
            const int s = sf*32 + m;
            const int r = s/17, q = s - 17*r;
            const int base = r*(2*IRS) + 12*q;
            u32x4 f1, f2;
            {   // frag1: row 2r+kg, words 6q+0..7  (khat 0..15)
                const char* rb = s_raw + base + kg*IRS;
                f1.x = *(const uint32*)(rb);
                f1.y = *(const uint32*)(rb + 4);
                f1.z = *(const uint32*)(rb + 8);
                f1.w = *(const uint32*)(rb + 12);
            }
            if (kg == 0) {      // khat 16..23: row 2r+2, words 6q+0..7
                const char* rc = s_raw + base + 2*IRS;
                f2.x = *(const uint32*)(rc);
                f2.y = *(const uint32*)(rc + 4);
                f2.z = *(const uint32*)(rc + 8);
                f2.w = *(const uint32*)(rc + 12);
            } else {            // khat 24..31: w8 of rows 2r,2r+1,2r+2, bias, 0
                uint32 a  = *(const unsigned short*)(s_raw + base + 16);
                uint32 bb = *(const unsigned short*)(s_raw + base + IRS + 16);
                uint32 cc = *(const unsigned short*)(s_raw + base + 2*IRS + 16);
                f2.x = a | (bb << 16);
                f2.y = cc | (0x3C00u << 16);     // f16 1.0 (bias multiplier)
                f2.z = 0; f2.w = 0;
            }
            f16x8 i0 = __builtin_bit_cast(f16x8, f1);
            f16x8 i1 = __builtin_bit_cast(f16x8, f2);
            f32x16 d;
            #pragma unroll
            for (int rr = 0; rr < 16; ++rr) d[rr] = 0.f;
            d = __builtin_amdgcn_mfma_f32_32x32x16_f16(wA, i0, d, 0, 0, 0);
            d = __builtin_amdgcn_mfma_f32_32x32x16_f16(wB, i1, d, 0, 0, 0);

            if (s < 289) {
                bool ok = (r0 + r < H1) && (q0 + q < H1);
                #pragma unroll
                for (int g = 0; g < 4; ++g) {     // ch = 8g + 4kg + (0..3)
                    bf16x4 vv;
                    #pragma unroll
                    for (int jj = 0; jj < 4; ++jj) {
                        float x = fmaxf(d[4*g + jj], 0.f);
                        vv[jj] = ok ? (bf16_t)x : (bf16_t)0.f;
                    }
                    *(bf16x4*)(s_c1b + SWZ(s, g) + kg*8) = vv;
                }
            }
        }
        __syncthreads();

        // ---- conv2 partial-K GEMM: conflict-free swizzled A, coalesced B ----
        const bf16_t* bP = bBase + (size_t)p*36*1024;
        #pragma unroll
        for (int kk = 0; kk < 9; ++kk) {
            const int dsh = (kk/3)*17 + (kk - 3*(kk/3));
            const int sA0 = s00 + dsh;
            const int sA1 = sA0 + 136;
            #pragma unroll
            for (int chh = 0; chh < 2; ++chh) {
                bf16x8 aF0 = *(const bf16x8*)(s_c1b + SWZ(sA0, 2*chh + kg));
                bf16x8 aF1 = *(const bf16x8*)(s_c1b + SWZ(sA1, 2*chh + kg));
                bf16x8 bF  = *(const bf16x8*)(bP + (size_t)(kk*4 + chh*2)*1024);
                acc0 = __builtin_amdgcn_mfma_f32_32x32x16_bf16(aF0, bF, acc0, 0, 0, 0);
                acc1 = __builtin_amdgcn_mfma_f32_32x32x16_bf16(aF1, bF, acc1, 0, 0, 0);
            }
        }
        __syncthreads();
    }

    // ---- epilogue: bias+ReLU, LDS transpose in two 64-ch halves ----
    {
        const int cOut = cg*32 + m;
        const float b2v = b2[cOut];
        const int sp = tid & 63;
        const int gyE = e0y + (sp >> 3), gxE = e0x + (sp & 7);
        const int c0 = tid >> 6;
        #pragma unroll 1
        for (int hf = 0; hf < 2; ++hf) {
            if ((cg >> 1) == hf) {
                const int cl = (cg & 1)*32 + m;
                #pragma unroll
                for (int r = 0; r < 16; ++r) {
                    int row = (r&3) + 8*(r>>2) + 4*kg;   // verified 32x32 C/D layout
                    s_ep[cl*66 + row]      = fmaxf(acc0[r] + b2v, 0.f);
                    s_ep[cl*66 + 32 + row] = fmaxf(acc1[r] + b2v, 0.f);
                }
            }
            __syncthreads();
            #pragma unroll
            for (int j = 0; j < 16; ++j) {
                int cl = c0 + 4*j;
                out[(size_t)(hf*64 + cl)*(H2*H2) + (size_t)gyE*H2 + gxE]
                    = s_ep[cl*66 + sp];
            }
            if (hf == 0) __syncthreads();
        }
    }
}

extern "C" void kernel_launch(void* const* d_in, const int* in_sizes, int n_in,
                              void* d_out, int out_size, void* d_ws, size_t ws_size,
                              hipStream_t stream) {
    const int*   img = (const int*)  d_in[0];
    const float* W1  = (const float*)d_in[1];
    const float* b1  = (const float*)d_in[2];
    const float* W2  = (const float*)d_in[3];
    const float* b2  = (const float*)d_in[4];
    float*       out = (float*)d_out;
    bf16_t*      W2T = (bf16_t*)d_ws;                          // 147456 B
    f16_t*       W1T = (f16_t*)((char*)d_ws + W2T_BYTES);      //   4096 B

    weights_transform<<<dim3(289), dim3(256), 0, stream>>>(W2, W1, b1, W2T, W1T);
    hms2_fused<<<dim3(NTB*NTB), dim3(256), 0, stream>>>(img, b2, W2T, W1T, out);
}

// Round 6
// 414.875 us; speedup vs baseline: 1.1326x; 1.1326x over previous
//
#include <hip/hip_runtime.h>

// HMS2 fused v7: = v6 structure (conv1 B-frags direct from f16 staged image,
// no im2col phase) with the spill fixed: __launch_bounds__(256,5) gives a
// 102-VGPR budget (v6's (256,6) capped at ~80 and spilled acc0/acc1 ->
// +350MB scratch HBM traffic). Staging loop vectorized (guarded int4 loads).
// LDS = s_imgf16(7424) + s_c1(18560) = 25984 B -> 5 blocks/CU (20 waves).

#define IMG 2304
#define H1  1152
#define H2  576
#define C1  64
#define C2  128
#define TS  8
#define NTB (H2/TS)        // 72
#define C1T 17
#define IT  35
#define IRS 212            // s_imgf16 row stride bytes (35*3*2=210 -> 212)
#define C1OFF 7424         // s_c1 base byte offset (128B aligned)

typedef __bf16 bf16_t;
typedef __bf16 bf16x8 __attribute__((ext_vector_type(8)));
typedef __bf16 bf16x4 __attribute__((ext_vector_type(4)));
typedef _Float16 f16_t;
typedef _Float16 f16x8 __attribute__((ext_vector_type(8)));
typedef float  f32x16 __attribute__((ext_vector_type(16)));
typedef unsigned int uint32;
typedef uint32 u32x4 __attribute__((ext_vector_type(4)));
typedef int    i32x4 __attribute__((ext_vector_type(4)));

#define W2T_BYTES (C2*576*2)     // 147456

// paired-row swizzle for s_c1: s = logical row (64B payload), g = 16B group 0..3
#define SWZ(s, g) ( (((s)>>1)*128) + (((((g) + (((s)&1)<<2) + (((s)>>1)&7)) & 7)) << 4) )

static __device__ __forceinline__ uint32 pack2f16(float a, float b) {
    union { f16_t h[2]; uint32 u; } x;
    x.h[0] = (f16_t)a; x.h[1] = (f16_t)b;
    return x.u;
}

// ---- merged weight transform: blocks 0..287 = W2 (coalesced reads),
//      block 288 = W1 (khat-reordered, bias at khat=27) ----
__global__ __launch_bounds__(256) void weights_transform(
    const float* __restrict__ W2, const float* __restrict__ W1,
    const float* __restrict__ b1,
    bf16_t* __restrict__ W2T, f16_t* __restrict__ W1T)
{
    if (blockIdx.x < 288) {
        int src = blockIdx.x*256 + threadIdx.x;            // linear over W2
        int n = src & 127, ci = (src >> 7) & 63, kykx = src >> 13;
        int p = ci >> 5, chh = (ci >> 4) & 1, kg = (ci >> 3) & 1, e = ci & 7;
        W2T[((((p*9 + kykx) << 2) + (chh << 1) + kg) << 10) + (n << 3) + e]
            = (bf16_t)W2[src];
    } else {
        int t = threadIdx.x;
        int oc = t & 63, grp = t >> 6;
        #pragma unroll
        for (int j = 0; j < 8; ++j) {
            int kh = grp*8 + j;
            float v;
            if (kh < 24)       v = W1[(9*(kh >> 3) + (kh & 7))*C1 + oc];
            else if (kh == 24) v = W1[ 8*C1 + oc];
            else if (kh == 25) v = W1[17*C1 + oc];
            else if (kh == 26) v = W1[26*C1 + oc];
            else if (kh == 27) v = b1[oc];
            else               v = 0.f;
            W1T[oc*32 + kh] = (f16_t)v;
        }
    }
}

__global__ __launch_bounds__(256, 5) void hms2_fused(
    const int*    __restrict__ img,
    const float*  __restrict__ b2,
    const bf16_t* __restrict__ W2T,
    const f16_t*  __restrict__ W1T,
    float*        __restrict__ out)
{
    __shared__ __align__(16) char s_raw[25984];
    // s_imgf16: row r (0..34) at byte r*IRS + 2*w, w = col*3+ch (0..104)
    char*  s_c1b = s_raw + C1OFF;               // [289 rows][64B] SWZ = 18560 B
    float* s_ep  = (float*)s_raw;               // 64*66 f32 = 16896 B (union)

    const int tid   = threadIdx.x;
    const int tileY = blockIdx.x / NTB;
    const int tileX = blockIdx.x % NTB;
    const int e0y = tileY*TS, e0x = tileX*TS;
    const int r0  = 2*e0y,    q0  = 2*e0x;
    const int iy0 = 4*e0y,    ix0 = 4*e0x;

    // ---- stage image tile as f16 (vectorized): 35 rows x 27 int4-groups ----
    const int cb = ix0*3;                        // word base within image row
    for (int g = tid; g < 35*27; g += 256) {
        int r  = g/27, w4 = g - 27*r;
        int gy = iy0 + r, wb = 4*w4;
        char* dst = s_raw + r*IRS + 2*wb;
        if (gy < IMG && w4 < 26 && (cb + wb + 3) < IMG*3) {
            i32x4 t = *(const i32x4*)(img + (size_t)gy*(IMG*3) + cb + wb);
            *(uint32*)(dst)     = pack2f16((float)t.x*(1.f/255.f), (float)t.y*(1.f/255.f));
            *(uint32*)(dst + 4) = pack2f16((float)t.z*(1.f/255.f), (float)t.w*(1.f/255.f));
        } else {
            #pragma unroll
            for (int e = 0; e < 4; ++e) {
                int w = wb + e;
                if (w < 105) {
                    float v = 0.f;
                    if (gy < IMG && (cb + w) < IMG*3)
                        v = (float)img[(size_t)gy*(IMG*3) + cb + w] * (1.f/255.f);
                    *(f16_t*)(s_raw + r*IRS + 2*w) = (f16_t)v;
                }
            }
        }
    }

    // ---- MFMA lane identities ----
    const int lane = tid & 63;
    const int m    = lane & 31;
    const int kg   = lane >> 5;
    const int cg   = __builtin_amdgcn_readfirstlane(tid >> 6);

    const int h0  = m >> 3, w0 = m & 7;
    const int s00 = 34*h0 + 2*w0;
    const bf16_t* bBase = W2T + (size_t)kg*1024 + (size_t)(cg*32 + m)*8;

    f32x16 acc0, acc1;
    #pragma unroll
    for (int r = 0; r < 16; ++r) { acc0[r] = 0.f; acc1[r] = 0.f; }

    __syncthreads();

    #pragma unroll 1
    for (int p = 0; p < 2; ++p) {
        // conv1 A-frags: W1T rows = out-channels [32p, 32p+32), khat order
        const f16_t* w1p = W1T + (size_t)(p*32 + m)*32 + kg*8;
        f16x8 wA = *(const f16x8*)(w1p);
        f16x8 wB = *(const f16x8*)(w1p + 16);

        // ---- conv1: B-frags direct from s_imgf16; D[ch][spatial] -> s_c1 ----
        for (int sf = cg; sf < 10; sf += 4) {
            const int s = sf*32 + m;
            const int r = s/17, q = s - 17*r;
            const int base = r*(2*IRS) + 12*q;
            u32x4 f1, f2;
            {   // frag1: row 2r+kg, words 6q+0..7  (khat 0..15)
                const char* rb = s_raw + base + kg*IRS;
                f1.x = *(const uint32*)(rb);
                f1.y = *(const uint32*)(rb + 4);
                f1.z = *(const uint32*)(rb + 8);
                f1.w = *(const uint32*)(rb + 12);
            }
            if (kg == 0) {      // khat 16..23: row 2r+2, words 6q+0..7
                const char* rc = s_raw + base + 2*IRS;
                f2.x = *(const uint32*)(rc);
                f2.y = *(const uint32*)(rc + 4);
                f2.z = *(const uint32*)(rc + 8);
                f2.w = *(const uint32*)(rc + 12);
            } else {            // khat 24..31: w8 of rows 2r,2r+1,2r+2, bias, 0
                uint32 a  = *(const unsigned short*)(s_raw + base + 16);
                uint32 bb = *(const unsigned short*)(s_raw + base + IRS + 16);
                uint32 cc = *(const unsigned short*)(s_raw + base + 2*IRS + 16);
                f2.x = a | (bb << 16);
                f2.y = cc | (0x3C00u << 16);     // f16 1.0 (bias multiplier)
                f2.z = 0; f2.w = 0;
            }
            f16x8 i0 = __builtin_bit_cast(f16x8, f1);
            f16x8 i1 = __builtin_bit_cast(f16x8, f2);
            f32x16 d;
            #pragma unroll
            for (int rr = 0; rr < 16; ++rr) d[rr] = 0.f;
            d = __builtin_amdgcn_mfma_f32_32x32x16_f16(wA, i0, d, 0, 0, 0);
            d = __builtin_amdgcn_mfma_f32_32x32x16_f16(wB, i1, d, 0, 0, 0);

            if (s < 289) {
                bool ok = (r0 + r < H1) && (q0 + q < H1);
                #pragma unroll
                for (int g = 0; g < 4; ++g) {     // ch = 8g + 4kg + (0..3)
                    bf16x4 vv;
                    #pragma unroll
                    for (int jj = 0; jj < 4; ++jj) {
                        float x = fmaxf(d[4*g + jj], 0.f);
                        vv[jj] = ok ? (bf16_t)x : (bf16_t)0.f;
                    }
                    *(bf16x4*)(s_c1b + SWZ(s, g) + kg*8) = vv;
                }
            }
        }
        __syncthreads();

        // ---- conv2 partial-K GEMM: conflict-free swizzled A, coalesced B ----
        const bf16_t* bP = bBase + (size_t)p*36*1024;
        #pragma unroll
        for (int kk = 0; kk < 9; ++kk) {
            const int dsh = (kk/3)*17 + (kk - 3*(kk/3));
            const int sA0 = s00 + dsh;
            const int sA1 = sA0 + 136;
            #pragma unroll
            for (int chh = 0; chh < 2; ++chh) {
                bf16x8 aF0 = *(const bf16x8*)(s_c1b + SWZ(sA0, 2*chh + kg));
                bf16x8 aF1 = *(const bf16x8*)(s_c1b + SWZ(sA1, 2*chh + kg));
                bf16x8 bF  = *(const bf16x8*)(bP + (size_t)(kk*4 + chh*2)*1024);
                acc0 = __builtin_amdgcn_mfma_f32_32x32x16_bf16(aF0, bF, acc0, 0, 0, 0);
                acc1 = __builtin_amdgcn_mfma_f32_32x32x16_bf16(aF1, bF, acc1, 0, 0, 0);
            }
        }
        __syncthreads();
    }

    // ---- epilogue: bias+ReLU, LDS transpose in two 64-ch halves ----
    {
        const float b2v = b2[cg*32 + m];
        const int sp = tid & 63;
        const int gyE = e0y + (sp >> 3), gxE = e0x + (sp & 7);
        const int c0 = tid >> 6;
        #pragma unroll 1
        for (int hf = 0; hf < 2; ++hf) {
            if ((cg >> 1) == hf) {
                const int cl = (cg & 1)*32 + m;
                #pragma unroll
                for (int r = 0; r < 16; ++r) {
                    int row = (r&3) + 8*(r>>2) + 4*kg;   // verified 32x32 C/D layout
                    s_ep[cl*66 + row]      = fmaxf(acc0[r] + b2v, 0.f);
                    s_ep[cl*66 + 32 + row] = fmaxf(acc1[r] + b2v, 0.f);
                }
            }
            __syncthreads();
            #pragma unroll
            for (int j = 0; j < 16; ++j) {
                int cl = c0 + 4*j;
                out[(size_t)(hf*64 + cl)*(H2*H2) + (size_t)gyE*H2 + gxE]
                    = s_ep[cl*66 + sp];
            }
            if (hf == 0) __syncthreads();
        }
    }
}

extern "C" void kernel_launch(void* const* d_in, const int* in_sizes, int n_in,
                              void* d_out, int out_size, void* d_ws, size_t ws_size,
                              hipStream_t stream) {
    const int*   img = (const int*)  d_in[0];
    const float* W1  = (const float*)d_in[1];
    const float* b1  = (const float*)d_in[2];
    const float* W2  = (const float*)d_in[3];
    const float* b2  = (const float*)d_in[4];
    float*       out = (float*)d_out;
    bf16_t*      W2T = (bf16_t*)d_ws;                          // 147456 B
    f16_t*       W1T = (f16_t*)((char*)d_ws + W2T_BYTES);      //   4096 B

    weights_transform<<<dim3(289), dim3(256), 0, stream>>>(W2, W1, b1, W2T, W1T);
    hms2_fused<<<dim3(NTB*NTB), dim3(256), 0, stream>>>(img, b2, W2T, W1T, out);
}

// Round 7
// 350.433 us; speedup vs baseline: 1.3409x; 1.1839x over previous
//
#include <hip/hip_runtime.h>

// HMS2 fused v8: = v7 structure (conv1 B-frags direct from f16 staged image,
// no im2col), spill ELIMINATED via __launch_bounds__(256,4) -> 128-VGPR
// budget (v7's (256,5) capped ~102 vs ~115 needed -> 19 dwords/thread scratch,
// +98MB HBM writes; v6's (256,6) was worse). 16 waves/CU, zero scratch.
// LDS = s_imgf16(7424) + s_c1(18560) = 25984 B.

#define IMG 2304
#define H1  1152
#define H2  576
#define C1  64
#define C2  128
#define TS  8
#define NTB (H2/TS)        // 72
#define C1T 17
#define IT  35
#define IRS 212            // s_imgf16 row stride bytes (35*3*2=210 -> 212)
#define C1OFF 7424         // s_c1 base byte offset (128B aligned)

typedef __bf16 bf16_t;
typedef __bf16 bf16x8 __attribute__((ext_vector_type(8)));
typedef __bf16 bf16x4 __attribute__((ext_vector_type(4)));
typedef _Float16 f16_t;
typedef _Float16 f16x8 __attribute__((ext_vector_type(8)));
typedef float  f32x16 __attribute__((ext_vector_type(16)));
typedef unsigned int uint32;
typedef uint32 u32x4 __attribute__((ext_vector_type(4)));
typedef int    i32x4 __attribute__((ext_vector_type(4)));

#define W2T_BYTES (C2*576*2)     // 147456

// paired-row swizzle for s_c1: s = logical row (64B payload), g = 16B group 0..3
#define SWZ(s, g) ( (((s)>>1)*128) + (((((g) + (((s)&1)<<2) + (((s)>>1)&7)) & 7)) << 4) )

static __device__ __forceinline__ uint32 pack2f16(float a, float b) {
    union { f16_t h[2]; uint32 u; } x;
    x.h[0] = (f16_t)a; x.h[1] = (f16_t)b;
    return x.u;
}

// ---- merged weight transform: blocks 0..287 = W2 (coalesced reads),
//      block 288 = W1 (khat-reordered, bias at khat=27) ----
__global__ __launch_bounds__(256) void weights_transform(
    const float* __restrict__ W2, const float* __restrict__ W1,
    const float* __restrict__ b1,
    bf16_t* __restrict__ W2T, f16_t* __restrict__ W1T)
{
    if (blockIdx.x < 288) {
        int src = blockIdx.x*256 + threadIdx.x;            // linear over W2
        int n = src & 127, ci = (src >> 7) & 63, kykx = src >> 13;
        int p = ci >> 5, chh = (ci >> 4) & 1, kg = (ci >> 3) & 1, e = ci & 7;
        W2T[((((p*9 + kykx) << 2) + (chh << 1) + kg) << 10) + (n << 3) + e]
            = (bf16_t)W2[src];
    } else {
        int t = threadIdx.x;
        int oc = t & 63, grp = t >> 6;
        #pragma unroll
        for (int j = 0; j < 8; ++j) {
            int kh = grp*8 + j;
            float v;
            if (kh < 24)       v = W1[(9*(kh >> 3) + (kh & 7))*C1 + oc];
            else if (kh == 24) v = W1[ 8*C1 + oc];
            else if (kh == 25) v = W1[17*C1 + oc];
            else if (kh == 26) v = W1[26*C1 + oc];
            else if (kh == 27) v = b1[oc];
            else               v = 0.f;
            W1T[oc*32 + kh] = (f16_t)v;
        }
    }
}

__global__ __launch_bounds__(256, 4) void hms2_fused(
    const int*    __restrict__ img,
    const float*  __restrict__ b2,
    const bf16_t* __restrict__ W2T,
    const f16_t*  __restrict__ W1T,
    float*        __restrict__ out)
{
    __shared__ __align__(16) char s_raw[25984];
    // s_imgf16: row r (0..34) at byte r*IRS + 2*w, w = col*3+ch (0..104)
    char*  s_c1b = s_raw + C1OFF;               // [289 rows][64B] SWZ = 18560 B
    float* s_ep  = (float*)s_raw;               // 64*66 f32 = 16896 B (union)

    const int tid   = threadIdx.x;
    const int tileY = blockIdx.x / NTB;
    const int tileX = blockIdx.x % NTB;
    const int e0y = tileY*TS, e0x = tileX*TS;
    const int r0  = 2*e0y,    q0  = 2*e0x;
    const int iy0 = 4*e0y,    ix0 = 4*e0x;

    // ---- stage image tile as f16 (vectorized): 35 rows x 27 int4-groups ----
    const int cb = ix0*3;                        // word base within image row
    for (int g = tid; g < 35*27; g += 256) {
        int r  = g/27, w4 = g - 27*r;
        int gy = iy0 + r, wb = 4*w4;
        char* dst = s_raw + r*IRS + 2*wb;
        if (gy < IMG && w4 < 26 && (cb + wb + 3) < IMG*3) {
            i32x4 t = *(const i32x4*)(img + (size_t)gy*(IMG*3) + cb + wb);
            *(uint32*)(dst)     = pack2f16((float)t.x*(1.f/255.f), (float)t.y*(1.f/255.f));
            *(uint32*)(dst + 4) = pack2f16((float)t.z*(1.f/255.f), (float)t.w*(1.f/255.f));
        } else {
            #pragma unroll
            for (int e = 0; e < 4; ++e) {
                int w = wb + e;
                if (w < 105) {
                    float v = 0.f;
                    if (gy < IMG && (cb + w) < IMG*3)
                        v = (float)img[(size_t)gy*(IMG*3) + cb + w] * (1.f/255.f);
                    *(f16_t*)(s_raw + r*IRS + 2*w) = (f16_t)v;
                }
            }
        }
    }

    // ---- MFMA lane identities ----
    const int lane = tid & 63;
    const int m    = lane & 31;
    const int kg   = lane >> 5;
    const int cg   = __builtin_amdgcn_readfirstlane(tid >> 6);

    const int h0  = m >> 3, w0 = m & 7;
    const int s00 = 34*h0 + 2*w0;
    const bf16_t* bBase = W2T + (size_t)kg*1024 + (size_t)(cg*32 + m)*8;

    f32x16 acc0, acc1;
    #pragma unroll
    for (int r = 0; r < 16; ++r) { acc0[r] = 0.f; acc1[r] = 0.f; }

    __syncthreads();

    #pragma unroll 1
    for (int p = 0; p < 2; ++p) {
        // conv1 A-frags: W1T rows = out-channels [32p, 32p+32), khat order
        const f16_t* w1p = W1T + (size_t)(p*32 + m)*32 + kg*8;
        f16x8 wA = *(const f16x8*)(w1p);
        f16x8 wB = *(const f16x8*)(w1p + 16);

        // ---- conv1: B-frags direct from s_imgf16; D[ch][spatial] -> s_c1 ----
        for (int sf = cg; sf < 10; sf += 4) {
            const int s = sf*32 + m;
            const int r = s/17, q = s - 17*r;
            const int base = r*(2*IRS) + 12*q;
            u32x4 f1, f2;
            {   // frag1: row 2r+kg, words 6q+0..7  (khat 0..15)
                const char* rb = s_raw + base + kg*IRS;
                f1.x = *(const uint32*)(rb);
                f1.y = *(const uint32*)(rb + 4);
                f1.z = *(const uint32*)(rb + 8);
                f1.w = *(const uint32*)(rb + 12);
            }
            if (kg == 0) {      // khat 16..23: row 2r+2, words 6q+0..7
                const char* rc = s_raw + base + 2*IRS;
                f2.x = *(const uint32*)(rc);
                f2.y = *(const uint32*)(rc + 4);
                f2.z = *(const uint32*)(rc + 8);
                f2.w = *(const uint32*)(rc + 12);
            } else {            // khat 24..31: w8 of rows 2r,2r+1,2r+2, bias, 0
                uint32 a  = *(const unsigned short*)(s_raw + base + 16);
                uint32 bb = *(const unsigned short*)(s_raw + base + IRS + 16);
                uint32 cc = *(const unsigned short*)(s_raw + base + 2*IRS + 16);
                f2.x = a | (bb << 16);
                f2.y = cc | (0x3C00u << 16);     // f16 1.0 (bias multiplier)
                f2.z = 0; f2.w = 0;
            }
            f16x8 i0 = __builtin_bit_cast(f16x8, f1);
            f16x8 i1 = __builtin_bit_cast(f16x8, f2);
            f32x16 d;
            #pragma unroll
            for (int rr = 0; rr < 16; ++rr) d[rr] = 0.f;
            d = __builtin_amdgcn_mfma_f32_32x32x16_f16(wA, i0, d, 0, 0, 0);
            d = __builtin_amdgcn_mfma_f32_32x32x16_f16(wB, i1, d, 0, 0, 0);

            if (s < 289) {
                bool ok = (r0 + r < H1) && (q0 + q < H1);
                #pragma unroll
                for (int g = 0; g < 4; ++g) {     // ch = 8g + 4kg + (0..3)
                    bf16x4 vv;
                    #pragma unroll
                    for (int jj = 0; jj < 4; ++jj) {
                        float x = fmaxf(d[4*g + jj], 0.f);
                        vv[jj] = ok ? (bf16_t)x : (bf16_t)0.f;
                    }
                    *(bf16x4*)(s_c1b + SWZ(s, g) + kg*8) = vv;
                }
            }
        }
        __syncthreads();

        // ---- conv2 partial-K GEMM: conflict-free swizzled A, coalesced B ----
        const bf16_t* bP = bBase + (size_t)p*36*1024;
        #pragma unroll
        for (int kk = 0; kk < 9; ++kk) {
            const int dsh = (kk/3)*17 + (kk - 3*(kk/3));
            const int sA0 = s00 + dsh;
            const int sA1 = sA0 + 136;
            #pragma unroll
            for (int chh = 0; chh < 2; ++chh) {
                bf16x8 aF0 = *(const bf16x8*)(s_c1b + SWZ(sA0, 2*chh + kg));
                bf16x8 aF1 = *(const bf16x8*)(s_c1b + SWZ(sA1, 2*chh + kg));
                bf16x8 bF  = *(const bf16x8*)(bP + (size_t)(kk*4 + chh*2)*1024);
                acc0 = __builtin_amdgcn_mfma_f32_32x32x16_bf16(aF0, bF, acc0, 0, 0, 0);
                acc1 = __builtin_amdgcn_mfma_f32_32x32x16_bf16(aF1, bF, acc1, 0, 0, 0);
            }
        }
        __syncthreads();
    }

    // ---- epilogue: bias+ReLU, LDS transpose in two 64-ch halves ----
    {
        const float b2v = b2[cg*32 + m];
        const int sp = tid & 63;
        const int gyE = e0y + (sp >> 3), gxE = e0x + (sp & 7);
        const int c0 = tid >> 6;
        #pragma unroll 1
        for (int hf = 0; hf < 2; ++hf) {
            if ((cg >> 1) == hf) {
                const int cl = (cg & 1)*32 + m;
                #pragma unroll
                for (int r = 0; r < 16; ++r) {
                    int row = (r&3) + 8*(r>>2) + 4*kg;   // verified 32x32 C/D layout
                    s_ep[cl*66 + row]      = fmaxf(acc0[r] + b2v, 0.f);
                    s_ep[cl*66 + 32 + row] = fmaxf(acc1[r] + b2v, 0.f);
                }
            }
            __syncthreads();
            #pragma unroll
            for (int j = 0; j < 16; ++j) {
                int cl = c0 + 4*j;
                out[(size_t)(hf*64 + cl)*(H2*H2) + (size_t)gyE*H2 + gxE]
                    = s_ep[cl*66 + sp];
            }
            if (hf == 0) __syncthreads();
        }
    }
}

extern "C" void kernel_launch(void* const* d_in, const int* in_sizes, int n_in,
                              void* d_out, int out_size, void* d_ws, size_t ws_size,
                              hipStream_t stream) {
    const int*   img = (const int*)  d_in[0];
    const float* W1  = (const float*)d_in[1];
    const float* b1  = (const float*)d_in[2];
    const float* W2  = (const float*)d_in[3];
    const float* b2  = (const float*)d_in[4];
    float*       out = (float*)d_out;
    bf16_t*      W2T = (bf16_t*)d_ws;                          // 147456 B
    f16_t*       W1T = (f16_t*)((char*)d_ws + W2T_BYTES);      //   4096 B

    weights_transform<<<dim3(289), dim3(256), 0, stream>>>(W2, W1, b1, W2T, W1T);
    hms2_fused<<<dim3(NTB*NTB), dim3(256), 0, stream>>>(img, b2, W2T, W1T, out);
}